// Round 4
// baseline (584.233 us; speedup 1.0000x reference)
//
#include <hip/hip_runtime.h>

// ParallelTransportUnpool:
//   out[dst[e], 0, ch, :] = x[c, 0, ch, :]
//   out[dst[e], 1, ch, :] = x[c, 1, ch, :] * conj(connection[e])
// where c = position of edge_src[e] in sorted unpool_nodes.
//
// V4: restore temporal locality on the x gather. Post-mortem of V2/V3b showed the
// bottleneck is the gather: each x row (2 KB) is used ~4x but uses are scattered
// across the whole launch -> effective HBM read ~410 MB instead of 102 MB.
// Fix: approximate counting-sort of edges by c (bucket = c>>6, ~128 KB of x per
// bucket). Main kernel walks edges in bucket order -> concurrent waves share a
// few-MB x window (L2/L3-resident) -> x fetched once. Output scatter is cheap
// (V2 vs V3b delta was only ~16 us) and stays nontemporal to protect the window.
//
// Pipeline (all in workspace): zero counts -> map[nodes[i]]=i -> histogram ->
// single-block exclusive scan -> scatter {c,dst,conn} records -> main.

typedef float v4f __attribute__((ext_vector_type(4)));

__global__ __launch_bounds__(256) void PTU_zero_kernel(
    int* __restrict__ count, int nb)
{
    int i = blockIdx.x * 256 + threadIdx.x;
    if (i < nb) count[i] = 0;
}

__global__ __launch_bounds__(256) void PTU_build_map_kernel(
    const int* __restrict__ nodes,   // (n_coarse,) sorted, values in [0, n_fine)
    int*       __restrict__ map,     // (n_fine,)
    int n_coarse)
{
    int i = blockIdx.x * 256 + threadIdx.x;
    if (i < n_coarse) map[nodes[i]] = i;
}

__global__ __launch_bounds__(256) void PTU_count_kernel(
    const int* __restrict__ map,
    const int* __restrict__ edge_src,
    int*       __restrict__ count,
    int n_fine, int shift)
{
    int e = blockIdx.x * 256 + threadIdx.x;
    if (e >= n_fine) return;
    int c = map[edge_src[e]];
    atomicAdd(&count[c >> shift], 1);
}

// Exclusive scan of count[0..nb) into tail[0..nb), nb <= 1024, one block.
__global__ __launch_bounds__(1024) void PTU_scan_kernel(
    const int* __restrict__ count,
    int*       __restrict__ tail,
    int nb)
{
    __shared__ int sm[1024];
    int t = threadIdx.x;
    int v = (t < nb) ? count[t] : 0;
    sm[t] = v;
    __syncthreads();
    for (int off = 1; off < 1024; off <<= 1) {
        int add = (t >= off) ? sm[t - off] : 0;
        __syncthreads();
        sm[t] += add;
        __syncthreads();
    }
    if (t < nb) tail[t] = sm[t] - v;   // exclusive prefix; doubles as running cursor
}

__global__ __launch_bounds__(256) void PTU_scatter_kernel(
    const int*    __restrict__ map,
    const float2* __restrict__ conn,
    const int*    __restrict__ edge_src,
    const int*    __restrict__ edge_dst,
    int*          __restrict__ tail,     // running cursors (start at bucket offsets)
    float4*       __restrict__ rec,      // (n_fine,) {c, dst, conn.x, conn.y}
    int n_fine, int shift)
{
    int e = blockIdx.x * 256 + threadIdx.x;
    if (e >= n_fine) return;
    int c = map[edge_src[e]];
    int pos = atomicAdd(&tail[c >> shift], 1);
    float2 b = conn[e];
    rec[pos] = make_float4(__int_as_float(c), __int_as_float(edge_dst[e]), b.x, b.y);
}

__global__ __launch_bounds__(256) void ParallelTransportUnpool_87582973100651_kernel(
    const float4* __restrict__ x,     // (N_COARSE, 2, 128, 2) = 128 float4/row
    const float4* __restrict__ rec,   // (N_FINE,) bucket-ordered by c
    float4*       __restrict__ out,   // (N_FINE, 2, 128, 2) = 128 float4/row
    int n_fine)
{
    // 4 records per 256-thread block; one wave (64 lanes) per record.
    // Records are c-bucket-ordered -> concurrent waves share an L2/L3-resident
    // x window; each x row is HBM-fetched once.
    int wv = threadIdx.x >> 6;
    int i  = blockIdx.x * 4 + wv;
    if (i >= n_fine) return;
    int lane = threadIdx.x & 63;

    float4 rv = rec[i];                               // wave-uniform 16B broadcast
    int   c  = __builtin_amdgcn_readfirstlane(__float_as_int(rv.x));
    int   d  = __builtin_amdgcn_readfirstlane(__float_as_int(rv.y));
    float br = rv.z;
    float bi = -rv.w;                                 // conj

    const float4* __restrict__ xr = x + (size_t)c * 128;
    float4 v0 = xr[lane];        // group 0
    float4 v1 = xr[lane + 64];   // group 1

    float4 t;
    t.x = v1.x * br - v1.y * bi;
    t.y = v1.x * bi + v1.y * br;
    t.z = v1.z * br - v1.w * bi;
    t.w = v1.z * bi + v1.w * br;

    float4* orow = out + (size_t)d * 128;
    // Nontemporal scatter: write-once data; keep the x window resident.
    v4f nv0 = { v0.x, v0.y, v0.z, v0.w };
    v4f nv1 = { t.x,  t.y,  t.z,  t.w  };
    __builtin_nontemporal_store(nv0, reinterpret_cast<v4f*>(&orow[lane]));
    __builtin_nontemporal_store(nv1, reinterpret_cast<v4f*>(&orow[lane + 64]));
}

// ---------- fallbacks ----------

__global__ __launch_bounds__(256) void PTU_map_scatter_kernel(
    const float4* __restrict__ x,
    const float2* __restrict__ conn,
    const int*    __restrict__ map,
    const int*    __restrict__ edge_src,
    const int*    __restrict__ edge_dst,
    float4*       __restrict__ out,
    int n_fine)
{
    int wv = __builtin_amdgcn_readfirstlane(threadIdx.x >> 6);
    int e  = blockIdx.x * 4 + wv;
    if (e >= n_fine) return;
    int lane = threadIdx.x & 63;

    int s = __builtin_amdgcn_readfirstlane(edge_src[e]);
    int d = __builtin_amdgcn_readfirstlane(edge_dst[e]);
    int c = __builtin_amdgcn_readfirstlane(map[s]);

    const float4* __restrict__ xr = x + (size_t)c * 128;
    float4 v0 = xr[lane];
    float4 v1 = xr[lane + 64];
    float2 b  = conn[e];

    float br = b.x, bi = -b.y;
    float4 t;
    t.x = v1.x * br - v1.y * bi;
    t.y = v1.x * bi + v1.y * br;
    t.z = v1.z * br - v1.w * bi;
    t.w = v1.z * bi + v1.w * br;

    float4* orow = out + (size_t)d * 128;
    orow[lane]      = v0;
    orow[lane + 64] = t;
}

__global__ __launch_bounds__(256) void PTU_bsearch_kernel(
    const float4* __restrict__ x,
    const float2* __restrict__ conn,
    const int*    __restrict__ nodes,
    const int*    __restrict__ edge_src,
    const int*    __restrict__ edge_dst,
    float4*       __restrict__ out,
    int n_fine, int n_coarse)
{
    int e = blockIdx.x * 2 + (threadIdx.x >> 7);
    if (e >= n_fine) return;
    int lane = threadIdx.x & 127;

    int s = edge_src[e];
    int d = edge_dst[e];

    int lo = 0, hi = n_coarse - 1;
    while (lo < hi) {
        int mid = (lo + hi) >> 1;
        if (nodes[mid] < s) lo = mid + 1; else hi = mid;
    }
    int c = lo;

    float4 v = x[(size_t)c * 128 + lane];
    if (lane >= 64) {
        float2 b = conn[e];
        float br = b.x, bi = -b.y;
        float4 t;
        t.x = v.x * br - v.y * bi;
        t.y = v.x * bi + v.y * br;
        t.z = v.z * br - v.w * bi;
        t.w = v.z * bi + v.w * br;
        v = t;
    }
    out[(size_t)d * 128 + lane] = v;
}

extern "C" void kernel_launch(void* const* d_in, const int* in_sizes, int n_in,
                              void* d_out, int out_size, void* d_ws, size_t ws_size,
                              hipStream_t stream) {
    const float4* x     = (const float4*)d_in[0];
    const float2* conn  = (const float2*)d_in[1];
    const int*    nodes = (const int*)d_in[2];
    const int*    edges = (const int*)d_in[3];   // (2, N_FINE): row0 = src, row1 = dst

    const int n_coarse = in_sizes[2];
    const int n_fine   = in_sizes[3] / 2;

    const int* edge_src = edges;
    const int* edge_dst = edges + n_fine;

    float4* out = (float4*)d_out;

    // Bucket shift: ~64 coarse rows (128 KB of x) per bucket; nb must fit one
    // scan block of 1024 threads.
    int shift = 6;
    while ((((long)n_coarse + (1 << shift) - 1) >> shift) > 1024) shift++;
    const int nb = (n_coarse + (1 << shift) - 1) >> shift;

    // Workspace layout: rec (16B/edge) | map (4B/node) | count (4KB) | tail (4KB)
    const size_t need_bucket = (size_t)n_fine * 16 + (size_t)n_fine * 4 + 2 * 1024 * 4;
    const size_t need_map    = (size_t)n_fine * 4;

    if (ws_size >= need_bucket) {
        float4* rec   = (float4*)d_ws;
        int*    map   = (int*)(rec + n_fine);
        int*    count = map + n_fine;
        int*    tail  = count + 1024;

        PTU_zero_kernel<<<(nb + 255) / 256, 256, 0, stream>>>(count, nb);

        int mblocks = (n_coarse + 255) / 256;
        PTU_build_map_kernel<<<mblocks, 256, 0, stream>>>(nodes, map, n_coarse);

        int eblocks = (n_fine + 255) / 256;
        PTU_count_kernel<<<eblocks, 256, 0, stream>>>(map, edge_src, count, n_fine, shift);

        PTU_scan_kernel<<<1, 1024, 0, stream>>>(count, tail, nb);

        PTU_scatter_kernel<<<eblocks, 256, 0, stream>>>(
            map, conn, edge_src, edge_dst, tail, rec, n_fine, shift);

        int blocks = (n_fine + 3) / 4;   // 4 records per block, 1 wave per record
        ParallelTransportUnpool_87582973100651_kernel<<<blocks, 256, 0, stream>>>(
            x, rec, out, n_fine);
    } else if (ws_size >= need_map) {
        int* map = (int*)d_ws;
        int mblocks = (n_coarse + 255) / 256;
        PTU_build_map_kernel<<<mblocks, 256, 0, stream>>>(nodes, map, n_coarse);

        int blocks = (n_fine + 3) / 4;
        PTU_map_scatter_kernel<<<blocks, 256, 0, stream>>>(
            x, conn, map, edge_src, edge_dst, out, n_fine);
    } else {
        int blocks = (n_fine + 1) / 2;
        PTU_bsearch_kernel<<<blocks, 256, 0, stream>>>(
            x, conn, nodes, edge_src, edge_dst, out, n_fine, n_coarse);
    }
}